// Round 2
// baseline (372.893 us; speedup 1.0000x reference)
//
#include <hip/hip_runtime.h>
#include <hip/hip_bf16.h>

typedef __bf16 bf16x4 __attribute__((ext_vector_type(4)));
typedef __bf16 bf16x8 __attribute__((ext_vector_type(8)));
typedef float floatx4 __attribute__((ext_vector_type(4)));

#define GLD16(gp, lp) __builtin_amdgcn_global_load_lds(                      \
    (const __attribute__((address_space(1))) void*)(gp),                     \
    (__attribute__((address_space(3))) void*)(lp), 16, 0, 0)

constexpr int Mdim = 16384;   // B*S
constexpr int Ndim = 3072;    // 3*D
constexpr int Kdim = 1024;    // D

static __device__ __forceinline__ bf16x8 cvt8(floatx4 lo, floatx4 hi) {
    bf16x8 r;
#pragma unroll
    for (int e = 0; e < 4; ++e) { r[e] = (__bf16)lo[e]; r[e + 4] = (__bf16)hi[e]; }
    return r;
}

// ===========================================================================
// FAST PATH (requires ws_size >= 40 MB)
// ===========================================================================

// --- prep 1: W_eff = W_qkv + LoRA fold, fp32 accumulate -> bf16 ------------
__global__ __launch_bounds__(256) void build_weff(
    const float* __restrict__ Wqkv,   // 3072 x 1024
    const float* __restrict__ Waq,    // 16 x 1024
    const float* __restrict__ Wbq,    // 1024 x 16
    const float* __restrict__ Wav,    // 16 x 1024
    const float* __restrict__ Wbv,    // 1024 x 16
    __hip_bfloat16* __restrict__ Weff)
{
    const int idx = (blockIdx.x * 256 + threadIdx.x) * 4;  // e*1024 + d
    const int e = idx >> 10;
    const int d = idx & 1023;
    floatx4 v = *(const floatx4*)(Wqkv + idx);
    if (e < 1024) {
#pragma unroll
        for (int r = 0; r < 16; ++r) {
            const float wb = Wbq[e * 16 + r];
            floatx4 wa = *(const floatx4*)(Waq + r * 1024 + d);
#pragma unroll
            for (int q = 0; q < 4; ++q) v[q] += wb * wa[q];
        }
    } else if (e >= 2048) {
        const int e2 = e - 2048;
#pragma unroll
        for (int r = 0; r < 16; ++r) {
            const float wb = Wbv[e2 * 16 + r];
            floatx4 wa = *(const floatx4*)(Wav + r * 1024 + d);
#pragma unroll
            for (int q = 0; q < 4; ++q) v[q] += wb * wa[q];
        }
    }
    bf16x4 o;
#pragma unroll
    for (int q = 0; q < 4; ++q) o[q] = (__bf16)v[q];
    *(bf16x4*)(Weff + idx) = o;
}

// --- prep 2: x fp32 -> bf16 -------------------------------------------------
__global__ __launch_bounds__(256) void cvt_x(
    const float* __restrict__ x, __hip_bfloat16* __restrict__ xb)
{
    const size_t idx = ((size_t)blockIdx.x * 256 + threadIdx.x) * 8;
    bf16x8 r = cvt8(*(const floatx4*)(x + idx), *(const floatx4*)(x + idx + 4));
    *(bf16x8*)(xb + idx) = r;
}

// --- main GEMM v3: 128x128 tile, BK=64, 4 waves, 2 blocks/CU ----------------
// Design: keep round-1's K-loop wins (both-sides XOR swizzle, counted
// vmcnt(8) full-tile prefetch, setprio) but restore tile-boundary TLP:
// 64 KiB LDS -> 2 barrier-independent blocks per CU, so one block's
// prologue/vmcnt/epilogue stalls are covered by the other's MFMA.
// Only 2 barriers per K-tile (vs 8 in round-1's 4-phase schedule).
__global__ __launch_bounds__(256, 2) void gemm_bf16_v3(
    const __hip_bfloat16* __restrict__ A,     // M x K bf16
    const __hip_bfloat16* __restrict__ Bw,    // N x K bf16 (W_eff)
    const float* __restrict__ bias,           // N fp32
    float* __restrict__ C)                    // M x N fp32
{
    constexpr int NT = Kdim / 64;                     // 16 K-tiles
    __shared__ __hip_bfloat16 lds[2][2][128 * 64];    // [buf][A/B][row*64+col] 64 KiB

    const int t    = threadIdx.x;
    const int wave = t >> 6;
    const int lane = t & 63;
    const int wm   = wave >> 1;       // 2x2 wave grid, 64x64 output each
    const int wn   = wave & 1;

    // XCD-aware block swizzle (3072 blocks, 3072 % 8 == 0 -> bijective)
    constexpr int NWG = (Mdim / 128) * (Ndim / 128);  // 3072
    const int bid = (blockIdx.x & 7) * (NWG >> 3) + (blockIdx.x >> 3);
    const int bx  = bid % (Ndim / 128);   // n fastest: neighbors share A-panel
    const int by  = bid / (Ndim / 128);
    const int m0  = by * 128;
    const int n0  = bx * 128;

    // --- staging geometry: LDS dest LINEAR (t*16 within each 32-row band);
    // bank swizzle applied by permuting the GLOBAL source column (rule #21).
    // Tile = 128 rows x 64 cols bf16 = 16 KiB per matrix = 4 GLD16/thread.
    const int srow0 = t >> 3;                              // 0..31
    const int scb_s = ((t & 7) * 16) ^ ((srow0 & 7) << 4); // swizzled src col-byte

#define STAGE_TILE(nb_, kt_) do {                                              \
    const __hip_bfloat16* _ga = A  + (size_t)(m0 + srow0) * Kdim               \
                                + (kt_) * 64 + (scb_s >> 1);                   \
    const __hip_bfloat16* _gb = Bw + (size_t)(n0 + srow0) * Kdim               \
                                + (kt_) * 64 + (scb_s >> 1);                   \
    char* _la = (char*)&lds[nb_][0][0] + t * 16;                               \
    char* _lb = (char*)&lds[nb_][1][0] + t * 16;                               \
    GLD16(_ga,                      _la);                                      \
    GLD16(_ga + (size_t)32 * Kdim,  _la + 4096);                               \
    GLD16(_ga + (size_t)64 * Kdim,  _la + 8192);                               \
    GLD16(_ga + (size_t)96 * Kdim,  _la + 12288);                              \
    GLD16(_gb,                      _lb);                                      \
    GLD16(_gb + (size_t)32 * Kdim,  _lb + 4096);                               \
    GLD16(_gb + (size_t)64 * Kdim,  _lb + 8192);                               \
    GLD16(_gb + (size_t)96 * Kdim,  _lb + 12288);                              \
} while (0)

    // --- frag-read geometry: row stride 128 B; row&7 == fm&7 for every frag
    // row (wm*64, i*16 both ≡ 0 mod 8) -> XOR byte bits 4-6 with (fm&7)<<4.
    const int fm   = lane & 15;
    const int fk2  = (lane >> 4) * 16;        // k-slice byte offset within 32-col half
    const int fxor = (fm & 7) << 4;
    const int cbs0 = fk2 ^ fxor;              // kk = 0 (k 0..31)
    const int cbs1 = (64 + fk2) ^ fxor;       // kk = 1 (k 32..63)

    floatx4 acc[4][4];
#pragma unroll
    for (int i = 0; i < 4; ++i)
#pragma unroll
        for (int j = 0; j < 4; ++j)
            acc[i][j] = (floatx4){0.f, 0.f, 0.f, 0.f};

    // prologue: stage tile 0 into buf 0
    STAGE_TILE(0, 0);

    for (int kt = 0; kt < NT; ++kt) {
        const int nb = kt & 1;
        // stage tile t+1 into buf nb^1 (its readers finished at tile t-1's
        // bottom barrier); then wait for tile t's 8 loads (8 newest may fly)
        if (kt + 1 < NT) {
            STAGE_TILE(nb ^ 1, kt + 1);
            asm volatile("s_waitcnt vmcnt(8)" ::: "memory");
        } else {
            asm volatile("s_waitcnt vmcnt(0)" ::: "memory");
        }
        __builtin_amdgcn_s_barrier();          // all waves' stages visible

        const char* Ab = (const char*)&lds[nb][0][0];
        const char* Bb = (const char*)&lds[nb][1][0];
        bf16x8 aq[2][4], bq[2][4];
#pragma unroll
        for (int i = 0; i < 4; ++i) {
            aq[0][i] = *(const bf16x8*)(Ab + (wm * 64 + i * 16 + fm) * 128 + cbs0);
            aq[1][i] = *(const bf16x8*)(Ab + (wm * 64 + i * 16 + fm) * 128 + cbs1);
            bq[0][i] = *(const bf16x8*)(Bb + (wn * 64 + i * 16 + fm) * 128 + cbs0);
            bq[1][i] = *(const bf16x8*)(Bb + (wn * 64 + i * 16 + fm) * 128 + cbs1);
        }
        __builtin_amdgcn_s_setprio(1);
#pragma unroll
        for (int kk = 0; kk < 2; ++kk)
#pragma unroll
            for (int i = 0; i < 4; ++i)
#pragma unroll
                for (int j = 0; j < 4; ++j)
                    acc[i][j] = __builtin_amdgcn_mfma_f32_16x16x32_bf16(
                        aq[kk][i], bq[kk][j], acc[i][j], 0, 0, 0);
        __builtin_amdgcn_s_setprio(0);
        if (kt + 1 < NT)
            __builtin_amdgcn_s_barrier();      // reads done before next stage
    }

    // epilogue: C/D layout col(n)=lane&15, row(m)=(lane>>4)*4 + reg
    const int cn = lane & 15;
    const int cm = (lane >> 4) * 4;
    float bv[4];
#pragma unroll
    for (int j = 0; j < 4; ++j)
        bv[j] = bias[n0 + wn * 64 + j * 16 + cn];

#pragma unroll
    for (int i = 0; i < 4; ++i) {
        const int m = m0 + wm * 64 + i * 16 + cm;
#pragma unroll
        for (int j = 0; j < 4; ++j) {
            const int n = n0 + wn * 64 + j * 16 + cn;
            const size_t base = (size_t)m * Ndim + n;
#pragma unroll
            for (int r = 0; r < 4; ++r)
                C[base + (size_t)r * Ndim] = acc[i][j][r] + bv[j];
        }
    }
#undef STAGE_TILE
}

// ===========================================================================
// FALLBACK PATH (R2, proven): used only if ws_size < 40 MB
// ===========================================================================

__global__ __launch_bounds__(256, 2) void gemm_bias_f32(
    const float* __restrict__ A, const float* __restrict__ Bw,
    const float* __restrict__ bias, float* __restrict__ C)
{
    constexpr int TK = 32;
    __shared__ __hip_bfloat16 As[128 * TK];
    __shared__ __hip_bfloat16 Bs[128 * TK];

    const int t    = threadIdx.x;
    const int wave = t >> 6;
    const int lane = t & 63;
    const int bx   = blockIdx.x % (Ndim / 128);
    const int by   = blockIdx.x / (Ndim / 128);
    const int m0   = by * 128;
    const int n0   = bx * 128;
    const int wm   = wave >> 1;
    const int wn   = wave & 1;
    const int srow = wave * 16 + (lane >> 2);
    const int scol = (lane & 3) * 8;

    const float* Ag0 = A  + (size_t)(m0 + srow) * Kdim + scol;
    const float* Ag1 = Ag0 + (size_t)64 * Kdim;
    const float* Bg0 = Bw + (size_t)(n0 + srow) * Kdim + scol;
    const float* Bg1 = Bg0 + (size_t)64 * Kdim;

    __hip_bfloat16* Al0 = &As[srow * TK + scol];
    __hip_bfloat16* Al1 = &As[(srow + 64) * TK + scol];
    __hip_bfloat16* Bl0 = &Bs[srow * TK + scol];
    __hip_bfloat16* Bl1 = &Bs[(srow + 64) * TK + scol];

    const int fm = lane & 15;
    const int fk = (lane >> 4) * 8;

    floatx4 acc[4][4];
#pragma unroll
    for (int i = 0; i < 4; ++i)
#pragma unroll
        for (int j = 0; j < 4; ++j)
            acc[i][j] = (floatx4){0.f, 0.f, 0.f, 0.f};

    for (int kt = 0; kt < Kdim; kt += TK) {
        bf16x8 a0 = cvt8(*(const floatx4*)(Ag0 + kt), *(const floatx4*)(Ag0 + kt + 4));
        bf16x8 a1 = cvt8(*(const floatx4*)(Ag1 + kt), *(const floatx4*)(Ag1 + kt + 4));
        bf16x8 b0 = cvt8(*(const floatx4*)(Bg0 + kt), *(const floatx4*)(Bg0 + kt + 4));
        bf16x8 b1 = cvt8(*(const floatx4*)(Bg1 + kt), *(const floatx4*)(Bg1 + kt + 4));
        __syncthreads();
        *(bf16x8*)Al0 = a0;
        *(bf16x8*)Al1 = a1;
        *(bf16x8*)Bl0 = b0;
        *(bf16x8*)Bl1 = b1;
        __syncthreads();

        bf16x8 af[4], bfr[4];
#pragma unroll
        for (int i = 0; i < 4; ++i) {
            af[i]  = *(const bf16x8*)&As[(wm * 64 + i * 16 + fm) * TK + fk];
            bfr[i] = *(const bf16x8*)&Bs[(wn * 64 + i * 16 + fm) * TK + fk];
        }
#pragma unroll
        for (int i = 0; i < 4; ++i)
#pragma unroll
            for (int j = 0; j < 4; ++j)
                acc[i][j] = __builtin_amdgcn_mfma_f32_16x16x32_bf16(af[i], bfr[j], acc[i][j], 0, 0, 0);
    }

    const int cn = lane & 15;
    const int cm = (lane >> 4) * 4;
    float bv[4];
#pragma unroll
    for (int j = 0; j < 4; ++j)
        bv[j] = bias[n0 + wn * 64 + j * 16 + cn];
#pragma unroll
    for (int i = 0; i < 4; ++i) {
        const int m = m0 + wm * 64 + i * 16 + cm;
#pragma unroll
        for (int j = 0; j < 4; ++j) {
            const int n = n0 + wn * 64 + j * 16 + cn;
            const size_t base = (size_t)m * Ndim + n;
#pragma unroll
            for (int r = 0; r < 4; ++r)
                C[base + (size_t)r * Ndim] = acc[i][j][r] + bv[j];
        }
    }
}

__global__ __launch_bounds__(256) void lora_rmw(
    const float* __restrict__ x,
    const float* __restrict__ Waq, const float* __restrict__ Wbq,
    const float* __restrict__ Wav, const float* __restrict__ Wbv,
    float* __restrict__ out)
{
    __shared__ float Pq[64][16];
    __shared__ float Pv[64][16];
    const int t  = threadIdx.x;
    const int m0 = blockIdx.x * 64;
    {
        const int row = t >> 2;
        const int r0  = (t & 3) * 4;
        float accq[4] = {0.f, 0.f, 0.f, 0.f};
        float accv[4] = {0.f, 0.f, 0.f, 0.f};
        const float* xr = x + (size_t)(m0 + row) * Kdim;
        for (int d = 0; d < Kdim; d += 4) {
            floatx4 xv = *(const floatx4*)(xr + d);
#pragma unroll
            for (int rr = 0; rr < 4; ++rr) {
                floatx4 wq = *(const floatx4*)(Waq + (size_t)(r0 + rr) * Kdim + d);
                floatx4 wv = *(const floatx4*)(Wav + (size_t)(r0 + rr) * Kdim + d);
#pragma unroll
                for (int e = 0; e < 4; ++e) {
                    accq[rr] += xv[e] * wq[e];
                    accv[rr] += xv[e] * wv[e];
                }
            }
        }
#pragma unroll
        for (int rr = 0; rr < 4; ++rr) {
            Pq[row][r0 + rr] = accq[rr];
            Pv[row][r0 + rr] = accv[rr];
        }
    }
    __syncthreads();
    const int col  = t * 8;
    const bool isq = col < 1024;
    const int nn0  = isq ? col : col - 1024;
    const int n    = isq ? col : col + 1024;
    const float* Wb = isq ? Wbq : Wbv;
    for (int row = 0; row < 64; ++row) {
        const float* P = isq ? Pq[row] : Pv[row];
        const size_t off = (size_t)(m0 + row) * Ndim + n;
        floatx4 o0 = *(const floatx4*)(out + off);
        floatx4 o1 = *(const floatx4*)(out + off + 4);
#pragma unroll
        for (int i = 0; i < 8; ++i) {
            floatx4 w0 = *(const floatx4*)(Wb + (size_t)(nn0 + i) * 16);
            floatx4 w1 = *(const floatx4*)(Wb + (size_t)(nn0 + i) * 16 + 4);
            floatx4 w2 = *(const floatx4*)(Wb + (size_t)(nn0 + i) * 16 + 8);
            floatx4 w3 = *(const floatx4*)(Wb + (size_t)(nn0 + i) * 16 + 12);
            float s = 0.f;
#pragma unroll
            for (int r = 0; r < 4; ++r)
                s += P[r] * w0[r] + P[r + 4] * w1[r] + P[r + 8] * w2[r] + P[r + 12] * w3[r];
            if (i < 4) o0[i] += s; else o1[i - 4] += s;
        }
        *(floatx4*)(out + off)     = o0;
        *(floatx4*)(out + off + 4) = o1;
    }
}

extern "C" void kernel_launch(void* const* d_in, const int* in_sizes, int n_in,
                              void* d_out, int out_size, void* d_ws, size_t ws_size,
                              hipStream_t stream)
{
    (void)in_sizes; (void)n_in; (void)out_size;
    const float* x    = (const float*)d_in[0];
    const float* Wqkv = (const float*)d_in[1];
    const float* bqkv = (const float*)d_in[2];
    const float* Waq  = (const float*)d_in[3];
    const float* Wbq  = (const float*)d_in[4];
    const float* Wav  = (const float*)d_in[5];
    const float* Wbv  = (const float*)d_in[6];
    float* out = (float*)d_out;

    const size_t WEFF_BYTES = (size_t)Ndim * Kdim * sizeof(__hip_bfloat16); // 6.3 MB
    const size_t XB_BYTES   = (size_t)Mdim * Kdim * sizeof(__hip_bfloat16); // 33.5 MB

    if (ws_size >= WEFF_BYTES + XB_BYTES) {
        // fast path: fold LoRA into bf16 W_eff, bf16 x, single MFMA GEMM
        __hip_bfloat16* Weff = (__hip_bfloat16*)d_ws;
        __hip_bfloat16* xb   = (__hip_bfloat16*)((char*)d_ws + WEFF_BYTES);
        build_weff<<<(Ndim * Kdim / 4) / 256, 256, 0, stream>>>(Wqkv, Waq, Wbq, Wav, Wbv, Weff);
        cvt_x<<<(int)(((size_t)Mdim * Kdim / 8) / 256), 256, 0, stream>>>(x, xb);
        gemm_bf16_v3<<<(Mdim / 128) * (Ndim / 128), 256, 0, stream>>>(xb, Weff, bqkv, out);
    } else {
        // fallback: R2 proven path (no scratch)
        gemm_bias_f32<<<(Mdim / 128) * (Ndim / 128), 256, 0, stream>>>(x, Wqkv, bqkv, out);
        lora_rmw<<<Mdim / 64, 256, 0, stream>>>(x, Waq, Wbq, Wav, Wbv, out);
    }
}